// Round 3
// baseline (287.141 us; speedup 1.0000x reference)
//
#include <hip/hip_runtime.h>

// YOLO layer: (64, 30, 152, 152) fp32 -> (64, 3*152*152, 10) fp32
// Memory-bound transpose + elementwise. Traffic floor ~355MB -> ~56us @6.29TB/s
// (m13 copy-mix ceiling). Harness score includes ~217us of fixed fill dispatches.
// R1: direct 160B-stride stores -> 117us kernel.
// R2: LDS-staged coalesced writeback, 40KB LDS, 1 pos/thread -> ~100us.
// R3: 2 pos/thread -> 20KB LDS -> 8 blocks/CU; conflict-free b128 staging.
// R5: NT dwordx2 loads -> kernel ~66us (5.4 TB/s), score 282.3.
// R6 (this round): 4 pos/thread -> all loads are 16B dwordx4 (copy-class width,
//     1KB/wave/instr); 40KB LDS -> 4 blocks/CU = 16 waves/CU (still >>9KB/CU
//     in-flight needed for 6.3TB/s @ ~900cyc latency). LDS write stride 10
//     float4s -> worst 2-way bank conflict (free per m136); readback contiguous.

constexpr int G    = 152;
constexpr int G2   = G * G;      // 23104
constexpr int NA   = 3;
constexpr int NOUT = 10;         // NUM_CLASSES + 7
constexpr int P4   = G2 / 4;     // 5776 float4-groups per (b,a) plane

typedef float floatx4 __attribute__((ext_vector_type(4)));

__device__ __forceinline__ float fast_sigmoid(float v) {
    return 1.0f / (1.0f + __expf(-v));
}

// grid = 4332 blocks x 256 threads; each thread owns 4 consecutive positions.
// 4332*256 = 64*3*5776 tiles the float4-groups exactly -> no bounds guard.
// G = 152 = 4*38 -> a thread's 4 positions always share a grid row.
__global__ __launch_bounds__(256) void yolo_kernel(
    const float* __restrict__ x,
    const int*   __restrict__ img_size_p,
    float*       __restrict__ out)
{
    __shared__ float lds[256 * 4 * NOUT];   // 40 KB: 1024 positions x 10 ch

    const int t   = threadIdx.x;
    const int idx = blockIdx.x * 256 + t;   // float4-group id

    // img_size: 1-element array, int32 per harness rules; hedge for fp32 bits.
    int iv = *img_size_p;
    float img_size = (iv > 0 && iv < (1 << 20)) ? (float)iv : __int_as_float(iv);
    const float stride = img_size / (float)G;   // 8.0

    const float aw[NA] = {12.0f, 19.0f, 40.0f};
    const float ah[NA] = {16.0f, 36.0f, 28.0f};

    const int pos4 = idx % P4;
    const int ba   = idx / P4;       // b*3 + a
    const int a    = ba % NA;

    const int pos = pos4 * 4;        // 16B-aligned; same grid row for all 4
    const int y   = pos / G;
    const int x0  = pos - y * G;

    // 10 coalesced 16B channel loads (lane stride 16B -> 1KB/wave/instr).
    // Nontemporal: input is read-once and exceeds L2/L3; don't retain.
    floatx4 p[NOUT];
    const float* xbase = x + (size_t)ba * (NOUT * G2) + pos;
#pragma unroll
    for (int ch = 0; ch < NOUT; ++ch)
        p[ch] = __builtin_nontemporal_load(
            reinterpret_cast<const floatx4*>(xbase + (size_t)ch * G2));

    const float anchor_w = (aw[a] / stride) * stride;
    const float anchor_h = (ah[a] / stride) * stride;

    // Stage to LDS: thread t owns float4-slots [t*10, t*10+10).
    // Start banks (40t)%32 = (8t)%32 over 8-lane service groups -> worst-case
    // 2-way conflict on ds_write_b128 (free per m136). Readback is contiguous.
    floatx4* l4 = reinterpret_cast<floatx4*>(lds);

    alignas(16) float buf[2 * NOUT];    // two positions at a time (reg pressure)
#pragma unroll
    for (int half = 0; half < 2; ++half) {
#pragma unroll
        for (int jj = 0; jj < 2; ++jj) {
            const int j = half * 2 + jj;
            const float v0 = p[0][j];
            const float v1 = p[1][j];
            const float v2 = p[2][j];
            const float v3 = p[3][j];
            const float v4 = p[4][j];
            const float v5 = p[5][j];
            const float v6 = p[6][j];
            const float v7 = p[7][j];
            const float v8 = p[8][j];
            const float v9 = p[9][j];

            const float bx = fast_sigmoid(v0) * 1.05f - 0.5f * (1.05f - 1.0f);
            const float by = fast_sigmoid(v1) * 1.05f - 0.5f * (1.05f - 1.0f);

            buf[jj * NOUT + 0] = (bx + (float)(x0 + j)) * stride;
            buf[jj * NOUT + 1] = (by + (float)y) * stride;
            buf[jj * NOUT + 2] = __expf(v2) * anchor_w;
            buf[jj * NOUT + 3] = __expf(v3) * anchor_h;
            buf[jj * NOUT + 4] = v4;
            buf[jj * NOUT + 5] = v5;
            buf[jj * NOUT + 6] = fast_sigmoid(v6);
            buf[jj * NOUT + 7] = fast_sigmoid(v7);
            buf[jj * NOUT + 8] = fast_sigmoid(v8);
            buf[jj * NOUT + 9] = fast_sigmoid(v9);
        }
        const floatx4* b4 = reinterpret_cast<const floatx4*>(buf);
#pragma unroll
        for (int w = 0; w < 5; ++w)
            l4[t * 10 + half * 5 + w] = b4[w];
    }

    __syncthreads();

    // Coalesced writeback: 10 rounds, lane i writes 16B at lane-stride 16B.
    // Nontemporal: output is write-once.
    floatx4* dst = reinterpret_cast<floatx4*>(out) + (size_t)blockIdx.x * (256 * 10);
#pragma unroll
    for (int r = 0; r < 10; ++r) {
        floatx4 v = l4[r * 256 + t];
        __builtin_nontemporal_store(v, dst + r * 256 + t);
    }
}

extern "C" void kernel_launch(void* const* d_in, const int* in_sizes, int n_in,
                              void* d_out, int out_size, void* d_ws, size_t ws_size,
                              hipStream_t stream) {
    const float* x = (const float*)d_in[0];
    const int* img_size_p = (const int*)d_in[1];
    float* out = (float*)d_out;

    const int total4 = 64 * NA * P4;          // 1,108,992 thread-groups
    const int blocks = total4 / 256;          // 4332, exact
    yolo_kernel<<<blocks, 256, 0, stream>>>(x, img_size_p, out);
}